// Round 4
// baseline (289.567 us; speedup 1.0000x reference)
//
#include <hip/hip_runtime.h>
#include <hip/hip_bf16.h>

#define BATCH 16384
#define FIN   768
#define FOUT  512

#define BM 128
#define BN 128
#define BK 32
#define NT (FIN / BK)   // 24 K-tiles

typedef __attribute__((ext_vector_type(8))) short short8;
typedef __attribute__((ext_vector_type(4))) float floatx4;

// packed fp32x2 -> bf16x2, round-to-nearest-even (gfx940+ VOP3)
__device__ __forceinline__ unsigned int cvt_pk_bf16(float a, float b) {
    unsigned int r;
    asm("v_cvt_pk_bf16_f32 %0, %1, %2" : "=v"(r) : "v"(a), "v"(b));
    return r;
}

// 8 fp32 (two float4, k ascending) -> bf16x8 MFMA fragment
__device__ __forceinline__ short8 pack_bf16(float4 lo, float4 hi) {
    union { short8 s; unsigned int u[4]; } r;
    r.u[0] = cvt_pk_bf16(lo.x, lo.y);
    r.u[1] = cvt_pk_bf16(lo.z, lo.w);
    r.u[2] = cvt_pk_bf16(hi.x, hi.y);
    r.u[3] = cvt_pk_bf16(hi.z, hi.w);
    return r.s;
}

// Barrier-free GEMM: no LDS. Each wave loads its MFMA fragments directly from
// global (A frag row = contiguous 32B of fp32), cvt_pk to bf16, MFMA.
// 1-deep register prefetch + full unroll -> loads stay in flight across
// iterations with fine-grained vmcnt (no __syncthreads to drain them).
// Epilogue: h = clip(acc+b1,0,1); partial = sum_cols h*W2; quad shuffle
// reduce -> atomicAdd ws[row].
__global__ __launch_bounds__(256, 2) void pn_gemm(
    const float* __restrict__ stm, const float* __restrict__ nstm,
    const float* __restrict__ W1, const float* __restrict__ b1,
    const float* __restrict__ W2, float* __restrict__ ws)
{
    const int tid  = threadIdx.x;
    const int lane = tid & 63;
    const int wave = tid >> 6;
    const int wm   = wave >> 1;
    const int wn   = wave & 1;
    const int quad = lane >> 4;
    const int l16  = lane & 15;

    // XCD swizzle: 4 col-tiles of one row-tile -> ids congruent mod 8 (same XCD L2)
    const int id = blockIdx.x;            // 0..1023
    const int g  = id >> 5;               // 32-block super-group = 8 rowTiles x 4 colTiles
    const int w5 = id & 31;
    const int rowTileIdx = g * 8 + (w5 & 7);   // 0..255
    const int colTile    = (w5 >> 3) * BN;     // 0,128,256,384
    const int rowTile    = rowTileIdx * BM;

    const int p = (rowTile >= BATCH) ? 1 : 0;
    const float* __restrict__ X = p ? nstm : stm;
    const int rowOff = rowTile - p * BATCH;

    // Fragment base pointers: lane reads k = quad*8 .. +7 (32 B contiguous)
    const float4* aP[4];
    const float4* bP[4];
    #pragma unroll
    for (int mi = 0; mi < 4; ++mi)
        aP[mi] = (const float4*)(X + (size_t)(rowOff + wm * 64 + mi * 16 + l16) * FIN + quad * 8);
    #pragma unroll
    for (int ni = 0; ni < 4; ++ni)
        bP[ni] = (const float4*)(W1 + (size_t)(colTile + wn * 64 + ni * 16 + l16) * FIN + quad * 8);

    floatx4 acc[4][4];
    #pragma unroll
    for (int i = 0; i < 4; ++i)
        #pragma unroll
        for (int j = 0; j < 4; ++j)
            acc[i][j] = (floatx4)0.0f;

    // double-buffered fp32 fragment registers (1-deep prefetch)
    float4 abuf[2][4][2], bbuf[2][4][2];

    #pragma unroll
    for (int mi = 0; mi < 4; ++mi) {
        abuf[0][mi][0] = aP[mi][0];
        abuf[0][mi][1] = aP[mi][1];
        bbuf[0][mi][0] = bP[mi][0];
        bbuf[0][mi][1] = bP[mi][1];
    }

    #pragma unroll
    for (int t = 0; t < NT; ++t) {
        const int cur = t & 1;
        const int nxt = cur ^ 1;

        if (t + 1 < NT) {
            // prefetch next K-tile's fragments (k advance = 8 float4s)
            #pragma unroll
            for (int mi = 0; mi < 4; ++mi) {
                abuf[nxt][mi][0] = aP[mi][(t + 1) * 8];
                abuf[nxt][mi][1] = aP[mi][(t + 1) * 8 + 1];
                bbuf[nxt][mi][0] = bP[mi][(t + 1) * 8];
                bbuf[nxt][mi][1] = bP[mi][(t + 1) * 8 + 1];
            }
        }

        short8 af[4], bfr[4];
        #pragma unroll
        for (int mi = 0; mi < 4; ++mi)
            af[mi] = pack_bf16(abuf[cur][mi][0], abuf[cur][mi][1]);
        #pragma unroll
        for (int ni = 0; ni < 4; ++ni)
            bfr[ni] = pack_bf16(bbuf[cur][ni][0], bbuf[cur][ni][1]);

        #pragma unroll
        for (int mi = 0; mi < 4; ++mi)
            #pragma unroll
            for (int ni = 0; ni < 4; ++ni)
                acc[mi][ni] = __builtin_amdgcn_mfma_f32_16x16x32_bf16(
                    af[mi], bfr[ni], acc[mi][ni], 0, 0, 0);
    }

    // epilogue: C/D layout col = lane&15, row = quad*4 + reg
    float b1v[4], w2v[4];
    #pragma unroll
    for (int ni = 0; ni < 4; ++ni) {
        int col = colTile + wn * 64 + ni * 16 + l16;
        b1v[ni] = b1[col];
        w2v[ni] = W2[p * FOUT + col];
    }

    const int rBase = rowOff + wm * 64;
    #pragma unroll
    for (int mi = 0; mi < 4; ++mi) {
        #pragma unroll
        for (int r = 0; r < 4; ++r) {
            float s = 0.0f;
            #pragma unroll
            for (int ni = 0; ni < 4; ++ni) {
                float h = acc[mi][ni][r] + b1v[ni];
                h = fminf(fmaxf(h, 0.0f), 1.0f);
                s += h * w2v[ni];
            }
            s += __shfl_xor(s, 1);
            s += __shfl_xor(s, 2);
            s += __shfl_xor(s, 4);
            s += __shfl_xor(s, 8);
            if (l16 == 0) {
                atomicAdd(&ws[rBase + mi * 16 + quad * 4 + r], s);
            }
        }
    }
}

__global__ __launch_bounds__(256) void pn_finalize(
    const float* __restrict__ ws, const float* __restrict__ b2,
    float* __restrict__ out)
{
    int i = blockIdx.x * blockDim.x + threadIdx.x;
    float x = ws[i] + b2[0];
    out[i] = 1.0f / (1.0f + expf(-x));
}

extern "C" void kernel_launch(void* const* d_in, const int* in_sizes, int n_in,
                              void* d_out, int out_size, void* d_ws, size_t ws_size,
                              hipStream_t stream)
{
    (void)in_sizes; (void)n_in; (void)out_size; (void)ws_size;
    const float* stm  = (const float*)d_in[0];
    const float* nstm = (const float*)d_in[1];
    const float* W1   = (const float*)d_in[2];
    const float* b1   = (const float*)d_in[3];
    const float* W2   = (const float*)d_in[4];
    const float* b2   = (const float*)d_in[5];
    float* out = (float*)d_out;
    float* ws  = (float*)d_ws;

    hipMemsetAsync(ws, 0, BATCH * sizeof(float), stream);

    dim3 grid((FOUT / BN) * ((2 * BATCH) / BM));   // 1024 blocks, 1D for swizzle
    pn_gemm<<<grid, dim3(256), 0, stream>>>(stm, nstm, W1, b1, W2, ws);
    pn_finalize<<<dim3(BATCH / 256), dim3(256), 0, stream>>>(ws, b2, out);
}

// Round 5
// 187.456 us; speedup vs baseline: 1.5447x; 1.5447x over previous
//
#include <hip/hip_runtime.h>
#include <hip/hip_bf16.h>

#define BATCH 16384
#define FIN   768
#define FOUT  512

#define BM 64
#define BN 128
#define BK 32
#define LDK 40   // bf16 padded stride (80 B): <=2-way LDS conflicts, 16B-aligned
#define NT (FIN / BK)   // 24 K-tiles

typedef __attribute__((ext_vector_type(8))) short short8;
typedef __attribute__((ext_vector_type(4))) float floatx4;

// packed fp32x2 -> bf16x2, round-to-nearest-even (gfx940+ VOP3)
__device__ __forceinline__ unsigned int cvt_pk_bf16(float a, float b) {
    unsigned int r;
    asm("v_cvt_pk_bf16_f32 %0, %1, %2" : "=v"(r) : "v"(a), "v"(b));
    return r;
}

__device__ __forceinline__ uint2 pack4(float4 v) {
    uint2 o;
    o.x = cvt_pk_bf16(v.x, v.y);
    o.y = cvt_pk_bf16(v.z, v.w);
    return o;
}

// 64x128 tile per block (2048 blocks = 8/CU): single-buffer LDS, cvt_pk
// staging, XCD swizzle. TLP (many small resident blocks) hides the
// per-iteration barrier/load-latency drain that R2-R4 showed is the limiter.
__global__ __launch_bounds__(256, 5) void pn_gemm(
    const float* __restrict__ stm, const float* __restrict__ nstm,
    const float* __restrict__ W1, const float* __restrict__ b1,
    const float* __restrict__ W2, float* __restrict__ ws)
{
    __shared__ __align__(16) unsigned short As[BM * LDK];
    __shared__ __align__(16) unsigned short Bs[BN * LDK];

    const int tid  = threadIdx.x;
    const int lane = tid & 63;
    const int wave = tid >> 6;
    const int wm   = wave >> 1;   // row half: rows wm*32 .. +31
    const int wn   = wave & 1;    // col half: cols wn*64 .. +63
    const int quad = lane >> 4;
    const int l16  = lane & 15;

    // XCD swizzle: 32-block super-group = 8 rowTiles x 4 colTiles -> ids
    // congruent mod 8 share a row-tile's X data on one XCD's L2.
    const int id = blockIdx.x;                 // 0..2047
    const int g  = id >> 5;                    // 0..63
    const int w5 = id & 31;
    const int rowTileIdx = g * 8 + (w5 & 7);   // 0..511
    const int colTile    = (w5 >> 3) * BN;     // 0,128,256,384
    const int rowTile    = rowTileIdx * BM;

    const int p = (rowTile >= BATCH) ? 1 : 0;
    const float* __restrict__ X = p ? nstm : stm;
    const int rowOff = rowTile - p * BATCH;

    // staging geometry: thread covers float4 slot sp4 of rows srow, srow+32(,+64,+96 for B)
    const int srow = tid >> 3;   // 0..31
    const int sp4  = tid & 7;    // 0..7

    const float* aPtr = X  + (size_t)(rowOff  + srow) * FIN + sp4 * 4;
    const float* bPtr = W1 + (size_t)(colTile + srow) * FIN + sp4 * 4;

    floatx4 acc[2][4];
    #pragma unroll
    for (int i = 0; i < 2; ++i)
        #pragma unroll
        for (int j = 0; j < 4; ++j)
            acc[i][j] = (floatx4)0.0f;

    for (int kt = 0; kt < FIN; kt += BK) {
        __syncthreads();
        // stage A: 64 rows x 32 k
        #pragma unroll
        for (int i = 0; i < 2; ++i) {
            float4 v = *(const float4*)(aPtr + kt + (size_t)(i * 32) * FIN);
            *(uint2*)(&As[(srow + i * 32) * LDK + sp4 * 4]) = pack4(v);
        }
        // stage B: 128 rows x 32 k
        #pragma unroll
        for (int i = 0; i < 4; ++i) {
            float4 v = *(const float4*)(bPtr + kt + (size_t)(i * 32) * FIN);
            *(uint2*)(&Bs[(srow + i * 32) * LDK + sp4 * 4]) = pack4(v);
        }
        __syncthreads();

        short8 af[2], bfr[4];
        #pragma unroll
        for (int mi = 0; mi < 2; ++mi)
            af[mi] = *(const short8*)(&As[(wm * 32 + mi * 16 + l16) * LDK + quad * 8]);
        #pragma unroll
        for (int ni = 0; ni < 4; ++ni)
            bfr[ni] = *(const short8*)(&Bs[(wn * 64 + ni * 16 + l16) * LDK + quad * 8]);

        #pragma unroll
        for (int mi = 0; mi < 2; ++mi)
            #pragma unroll
            for (int ni = 0; ni < 4; ++ni)
                acc[mi][ni] = __builtin_amdgcn_mfma_f32_16x16x32_bf16(
                    af[mi], bfr[ni], acc[mi][ni], 0, 0, 0);
    }

    // epilogue: C/D layout col = lane&15, row = quad*4 + reg
    float b1v[4], w2v[4];
    #pragma unroll
    for (int ni = 0; ni < 4; ++ni) {
        int col = colTile + wn * 64 + ni * 16 + l16;
        b1v[ni] = b1[col];
        w2v[ni] = W2[p * FOUT + col];
    }

    const int rBase = rowOff + wm * 32;
    #pragma unroll
    for (int mi = 0; mi < 2; ++mi) {
        #pragma unroll
        for (int r = 0; r < 4; ++r) {
            float s = 0.0f;
            #pragma unroll
            for (int ni = 0; ni < 4; ++ni) {
                float h = acc[mi][ni][r] + b1v[ni];
                h = fminf(fmaxf(h, 0.0f), 1.0f);
                s += h * w2v[ni];
            }
            s += __shfl_xor(s, 1);
            s += __shfl_xor(s, 2);
            s += __shfl_xor(s, 4);
            s += __shfl_xor(s, 8);
            if (l16 == 0) {
                atomicAdd(&ws[rBase + mi * 16 + quad * 4 + r], s);
            }
        }
    }
}

__global__ __launch_bounds__(256) void pn_finalize(
    const float* __restrict__ ws, const float* __restrict__ b2,
    float* __restrict__ out)
{
    int i = blockIdx.x * blockDim.x + threadIdx.x;
    float x = ws[i] + b2[0];
    out[i] = 1.0f / (1.0f + expf(-x));
}

extern "C" void kernel_launch(void* const* d_in, const int* in_sizes, int n_in,
                              void* d_out, int out_size, void* d_ws, size_t ws_size,
                              hipStream_t stream)
{
    (void)in_sizes; (void)n_in; (void)out_size; (void)ws_size;
    const float* stm  = (const float*)d_in[0];
    const float* nstm = (const float*)d_in[1];
    const float* W1   = (const float*)d_in[2];
    const float* b1   = (const float*)d_in[3];
    const float* W2   = (const float*)d_in[4];
    const float* b2   = (const float*)d_in[5];
    float* out = (float*)d_out;
    float* ws  = (float*)d_ws;

    hipMemsetAsync(ws, 0, BATCH * sizeof(float), stream);

    dim3 grid((FOUT / BN) * ((2 * BATCH) / BM));   // 4 * 512 = 2048 blocks
    pn_gemm<<<grid, dim3(256), 0, stream>>>(stm, nstm, W1, b1, W2, ws);
    pn_finalize<<<dim3(BATCH / 256), dim3(256), 0, stream>>>(ws, b2, out);
}

// Round 6
// 162.499 us; speedup vs baseline: 1.7820x; 1.1536x over previous
//
#include <hip/hip_runtime.h>
#include <hip/hip_bf16.h>

#define BATCH 16384
#define FIN   768
#define FOUT  512

#define BM 128
#define BN 256
#define BK 32
#define LDK 40   // bf16 padded stride (80 B): <=2-way LDS conflicts, 16B-aligned
#define W1B_OFF 65536   // byte offset of bf16 W1 inside d_ws (after 16384 fp32 partials)

typedef __attribute__((ext_vector_type(8))) short short8;
typedef __attribute__((ext_vector_type(4))) float floatx4;

// packed fp32x2 -> bf16x2, round-to-nearest-even (gfx940+ VOP3)
__device__ __forceinline__ unsigned int cvt_pk_bf16(float a, float b) {
    unsigned int r;
    asm("v_cvt_pk_bf16_f32 %0, %1, %2" : "=v"(r) : "v"(a), "v"(b));
    return r;
}

__device__ __forceinline__ uint2 pack4(float4 v) {
    uint2 o;
    o.x = cvt_pk_bf16(v.x, v.y);
    o.y = cvt_pk_bf16(v.z, v.w);
    return o;
}

// one-shot W1 fp32 -> bf16 (393216 elems, 8 per thread)
__global__ __launch_bounds__(256) void cvt_w1(
    const float* __restrict__ W1, unsigned short* __restrict__ W1b)
{
    int base = (blockIdx.x * 256 + threadIdx.x) * 8;
    float4 a = *(const float4*)(W1 + base);
    float4 b = *(const float4*)(W1 + base + 4);
    uint4 o;
    uint2 pa = pack4(a), pb = pack4(b);
    o.x = pa.x; o.y = pa.y; o.z = pb.x; o.w = pb.y;
    *(uint4*)(W1b + base) = o;
}

// 128x256 tile per block (512 blocks): A staged fp32->bf16 (cvt_pk), B staged
// as pre-converted bf16 (plain 16B copies). Cuts L2 read traffic 1.2GB -> 0.4GB
// vs R5 (W1 re-read x512 -> x256 at half the bytes; X x4 -> x2).
__global__ __launch_bounds__(512, 4) void pn_gemm(
    const float* __restrict__ stm, const float* __restrict__ nstm,
    const unsigned short* __restrict__ W1b, const float* __restrict__ b1,
    const float* __restrict__ W2, float* __restrict__ ws)
{
    __shared__ __align__(16) unsigned short As[BM * LDK];
    __shared__ __align__(16) unsigned short Bs[BN * LDK];

    const int tid  = threadIdx.x;
    const int lane = tid & 63;
    const int wave = tid >> 6;    // 0..7
    const int wm   = wave >> 2;   // row half (0..1): rows wm*64..+63
    const int wn   = wave & 3;    // col quarter (0..3): cols wn*64..+63
    const int quad = lane >> 4;
    const int l16  = lane & 15;

    // XCD swizzle: 16-block group = 8 rowTiles x 2 colTiles; ids congruent
    // mod 8 (same XCD) share one row-tile's X.
    const int id = blockIdx.x;                 // 0..511
    const int w4 = id & 15;
    const int rowTileIdx = (id >> 4) * 8 + (w4 & 7);   // 0..255
    const int colTile    = (w4 >> 3) * BN;             // 0 or 256
    const int rowTile    = rowTileIdx * BM;

    const int p = (rowTile >= BATCH) ? 1 : 0;
    const float* __restrict__ X = p ? nstm : stm;
    const int rowOff = rowTile - p * BATCH;

    // A staging: 1024 float4s over 512 threads (2 each)
    const int arow = tid >> 3;   // 0..63 (+64 for i=1)
    const int asp4 = tid & 7;
    // B staging: 1024 16B-chunks over 512 threads (2 each)
    const int bcol = tid >> 2;   // 0..127 (+128 for i=1)
    const int bc16 = tid & 3;

    const float* aPtr = X + (size_t)(rowOff + arow) * FIN + asp4 * 4;
    const unsigned short* bPtr = W1b + (size_t)(colTile + bcol) * FIN + bc16 * 8;

    floatx4 acc[4][4];
    #pragma unroll
    for (int i = 0; i < 4; ++i)
        #pragma unroll
        for (int j = 0; j < 4; ++j)
            acc[i][j] = (floatx4)0.0f;

    for (int kt = 0; kt < FIN; kt += BK) {
        __syncthreads();
        #pragma unroll
        for (int i = 0; i < 2; ++i) {
            float4 v = *(const float4*)(aPtr + kt + (size_t)(i * 64) * FIN);
            *(uint2*)(&As[(arow + i * 64) * LDK + asp4 * 4]) = pack4(v);
        }
        #pragma unroll
        for (int i = 0; i < 2; ++i) {
            uint4 v = *(const uint4*)(bPtr + kt + (size_t)(i * 128) * FIN);
            *(uint4*)(&Bs[(bcol + i * 128) * LDK + bc16 * 8]) = v;
        }
        __syncthreads();

        short8 af[4], bfr[4];
        #pragma unroll
        for (int mi = 0; mi < 4; ++mi)
            af[mi] = *(const short8*)(&As[(wm * 64 + mi * 16 + l16) * LDK + quad * 8]);
        #pragma unroll
        for (int ni = 0; ni < 4; ++ni)
            bfr[ni] = *(const short8*)(&Bs[(wn * 64 + ni * 16 + l16) * LDK + quad * 8]);

        #pragma unroll
        for (int mi = 0; mi < 4; ++mi)
            #pragma unroll
            for (int ni = 0; ni < 4; ++ni)
                acc[mi][ni] = __builtin_amdgcn_mfma_f32_16x16x32_bf16(
                    af[mi], bfr[ni], acc[mi][ni], 0, 0, 0);
    }

    // epilogue: C/D layout col = lane&15, row = quad*4 + reg
    float b1v[4], w2v[4];
    #pragma unroll
    for (int ni = 0; ni < 4; ++ni) {
        int col = colTile + wn * 64 + ni * 16 + l16;
        b1v[ni] = b1[col];
        w2v[ni] = W2[p * FOUT + col];
    }

    const int rBase = rowOff + wm * 64;
    #pragma unroll
    for (int mi = 0; mi < 4; ++mi) {
        #pragma unroll
        for (int r = 0; r < 4; ++r) {
            float s = 0.0f;
            #pragma unroll
            for (int ni = 0; ni < 4; ++ni) {
                float h = acc[mi][ni][r] + b1v[ni];
                h = fminf(fmaxf(h, 0.0f), 1.0f);
                s += h * w2v[ni];
            }
            s += __shfl_xor(s, 1);
            s += __shfl_xor(s, 2);
            s += __shfl_xor(s, 4);
            s += __shfl_xor(s, 8);
            if (l16 == 0) {
                atomicAdd(&ws[rBase + mi * 16 + quad * 4 + r], s);
            }
        }
    }
}

__global__ __launch_bounds__(256) void pn_finalize(
    const float* __restrict__ ws, const float* __restrict__ b2,
    float* __restrict__ out)
{
    int i = blockIdx.x * blockDim.x + threadIdx.x;
    float x = ws[i] + b2[0];
    out[i] = 1.0f / (1.0f + expf(-x));
}

extern "C" void kernel_launch(void* const* d_in, const int* in_sizes, int n_in,
                              void* d_out, int out_size, void* d_ws, size_t ws_size,
                              hipStream_t stream)
{
    (void)in_sizes; (void)n_in; (void)out_size; (void)ws_size;
    const float* stm  = (const float*)d_in[0];
    const float* nstm = (const float*)d_in[1];
    const float* W1   = (const float*)d_in[2];
    const float* b1   = (const float*)d_in[3];
    const float* W2   = (const float*)d_in[4];
    const float* b2   = (const float*)d_in[5];
    float* out = (float*)d_out;
    float* ws  = (float*)d_ws;                                  // [0, 64KB): fp32 partials
    unsigned short* W1b = (unsigned short*)((char*)d_ws + W1B_OFF);  // bf16 W1 copy

    hipMemsetAsync(ws, 0, BATCH * sizeof(float), stream);
    cvt_w1<<<dim3((FOUT * FIN) / (256 * 8)), dim3(256), 0, stream>>>(W1, W1b);

    dim3 grid((FOUT / BN) * ((2 * BATCH) / BM));   // 2 * 256 = 512 blocks
    pn_gemm<<<grid, dim3(512), 0, stream>>>(stm, nstm, W1b, b1, W2, ws);
    pn_finalize<<<dim3(BATCH / 256), dim3(256), 0, stream>>>(ws, b2, out);
}

// Round 7
// 161.633 us; speedup vs baseline: 1.7915x; 1.0054x over previous
//
#include <hip/hip_runtime.h>
#include <hip/hip_bf16.h>

#define BATCH 16384
#define FIN   768
#define FOUT  512

#define BM 128
#define BN 128
#define BK 64
#define LDKA 72            // A LDS stride in bf16 elems (144 B = 36 banks): ~2-way max
#define NT (FIN / BK)      // 12 K-iterations
#define W1B_OFF 65536      // byte offset of bf16 W1 inside d_ws (after 16384 fp32 partials)

typedef __attribute__((ext_vector_type(8))) short short8;
typedef __attribute__((ext_vector_type(4))) float floatx4;

// packed fp32x2 -> bf16x2, round-to-nearest-even (gfx940+ VOP3)
__device__ __forceinline__ unsigned int cvt_pk_bf16(float a, float b) {
    unsigned int r;
    asm("v_cvt_pk_bf16_f32 %0, %1, %2" : "=v"(r) : "v"(a), "v"(b));
    return r;
}

__device__ __forceinline__ uint2 pack4(float4 v) {
    uint2 o;
    o.x = cvt_pk_bf16(v.x, v.y);
    o.y = cvt_pk_bf16(v.z, v.w);
    return o;
}

// async 16B global -> LDS DMA; HW scatters lane i to ldsbase + i*16
__device__ __forceinline__ void load_lds_16(const void* g, void* l) {
    __builtin_amdgcn_global_load_lds(
        (const __attribute__((address_space(1))) unsigned int*)g,
        (__attribute__((address_space(3))) unsigned int*)l,
        16, 0, 0);
}

// one-shot W1 fp32 -> bf16 (393216 elems, 8 per thread)
__global__ __launch_bounds__(256) void cvt_w1(
    const float* __restrict__ W1, unsigned short* __restrict__ W1b)
{
    int base = (blockIdx.x * 256 + threadIdx.x) * 8;
    float4 a = *(const float4*)(W1 + base);
    float4 b = *(const float4*)(W1 + base + 4);
    uint2 pa = pack4(a), pb = pack4(b);
    uint4 o; o.x = pa.x; o.y = pa.y; o.z = pb.x; o.w = pb.y;
    *(uint4*)(W1b + base) = o;
}

// 128x128 tile, BK=64 (12 barriers), 256 thr, grid 1024 = 4 blocks/CU.
// B staged by global_load_lds DMA (bf16, XOR-chunk-swizzled source so the
// lane-order LDS layout gives conflict-free b128 reads). A staged via
// cvt_pk into padded LDS. Epilogue fuses b1 + clip + W2-dot -> atomicAdd.
__global__ __launch_bounds__(256, 4) void pn_gemm(
    const float* __restrict__ stm, const float* __restrict__ nstm,
    const unsigned short* __restrict__ W1b, const float* __restrict__ b1,
    const float* __restrict__ W2, float* __restrict__ ws)
{
    __shared__ __align__(16) unsigned short As[BM * LDKA];  // 18.4 KB
    __shared__ __align__(16) unsigned short Bs[BN * BK];    // 16.0 KB, unpadded (DMA layout)

    const int tid  = threadIdx.x;
    const int lane = tid & 63;
    const int wave = tid >> 6;    // 0..3
    const int wm   = wave >> 1;   // row half: rows wm*64..+63
    const int wn   = wave & 1;    // col half: cols wn*64..+63
    const int quad = lane >> 4;
    const int l16  = lane & 15;

    // XCD swizzle: 32-block group = 8 rowTiles x 4 colTiles; ids congruent
    // mod 8 (same XCD) share one row-tile's X in that XCD's L2.
    const int id = blockIdx.x;                 // 0..1023
    const int g  = id >> 5;
    const int w5 = id & 31;
    const int rowTileIdx = g * 8 + (w5 & 7);   // 0..255
    const int colTile    = (w5 >> 3) * BN;     // 0,128,256,384
    const int rowTile    = rowTileIdx * BM;

    const int p = (rowTile >= BATCH) ? 1 : 0;
    const float* __restrict__ X = p ? nstm : stm;
    const int rowOff = rowTile - p * BATCH;

    // A staging: 128 rows x 16 float4 = 2048 f4 / 256 thr = 8 each
    const int arow = tid >> 4;    // 0..15 (+16 per i)
    const int asp4 = tid & 15;    // float4 slot in the 64-k chunk
    const float* aPtr = X + (size_t)(rowOff + arow) * FIN + asp4 * 4;

    // B staging: 1024 16B-slots = 16 wave-loads (J = wave + i*4, i=0..3)
    // slot m = J*64 + lane -> row = J*8 + (lane>>3), cpos = lane&7;
    // source chunk gc = cpos ^ (row&7)  (XOR swizzle)
    const int bRowInJ = lane >> 3;              // 0..7
    const int bgc     = (lane & 7) ^ bRowInJ;   // swizzled source chunk

    floatx4 acc[4][4];
    #pragma unroll
    for (int i = 0; i < 4; ++i)
        #pragma unroll
        for (int j = 0; j < 4; ++j)
            acc[i][j] = (floatx4)0.0f;

    for (int t = 0; t < NT; ++t) {
        const int kt = t * BK;
        __syncthreads();

        // B: async DMA straight to LDS (no VGPR round-trip, no cvt)
        #pragma unroll
        for (int i = 0; i < 4; ++i) {
            const int J = wave + i * 4;               // wave-uniform
            const int row = J * 8 + bRowInJ;
            load_lds_16(W1b + (size_t)(colTile + row) * FIN + kt + bgc * 8,
                        &Bs[J * 512]);
        }
        // A: load fp32, cvt_pk, store bf16 (overlaps the B DMA)
        #pragma unroll
        for (int i = 0; i < 8; ++i) {
            float4 v = *(const float4*)(aPtr + kt + (size_t)(i * 16) * FIN);
            *(uint2*)(&As[(arow + i * 16) * LDKA + asp4 * 4]) = pack4(v);
        }
        __syncthreads();

        // 2 k-steps of 16x16x32 MFMA: 32 MFMA/wave per barrier pair
        #pragma unroll
        for (int s = 0; s < 2; ++s) {
            short8 af[4], bfr[4];
            #pragma unroll
            for (int mi = 0; mi < 4; ++mi)
                af[mi] = *(const short8*)(
                    &As[(wm * 64 + mi * 16 + l16) * LDKA + s * 32 + quad * 8]);
            #pragma unroll
            for (int ni = 0; ni < 4; ++ni) {
                const int r = wn * 64 + ni * 16 + l16;
                bfr[ni] = *(const short8*)(
                    &Bs[r * 64 + (((s * 4 + quad) ^ (r & 7)) * 8)]);
            }
            #pragma unroll
            for (int mi = 0; mi < 4; ++mi)
                #pragma unroll
                for (int ni = 0; ni < 4; ++ni)
                    acc[mi][ni] = __builtin_amdgcn_mfma_f32_16x16x32_bf16(
                        af[mi], bfr[ni], acc[mi][ni], 0, 0, 0);
        }
    }

    // epilogue: C/D layout col = lane&15, row = quad*4 + reg
    float b1v[4], w2v[4];
    #pragma unroll
    for (int ni = 0; ni < 4; ++ni) {
        int col = colTile + wn * 64 + ni * 16 + l16;
        b1v[ni] = b1[col];
        w2v[ni] = W2[p * FOUT + col];
    }

    const int rBase = rowOff + wm * 64;
    #pragma unroll
    for (int mi = 0; mi < 4; ++mi) {
        #pragma unroll
        for (int r = 0; r < 4; ++r) {
            float s = 0.0f;
            #pragma unroll
            for (int ni = 0; ni < 4; ++ni) {
                float h = acc[mi][ni][r] + b1v[ni];
                h = fminf(fmaxf(h, 0.0f), 1.0f);
                s += h * w2v[ni];
            }
            s += __shfl_xor(s, 1);
            s += __shfl_xor(s, 2);
            s += __shfl_xor(s, 4);
            s += __shfl_xor(s, 8);
            if (l16 == 0) {
                atomicAdd(&ws[rBase + mi * 16 + quad * 4 + r], s);
            }
        }
    }
}

__global__ __launch_bounds__(256) void pn_finalize(
    const float* __restrict__ ws, const float* __restrict__ b2,
    float* __restrict__ out)
{
    int i = blockIdx.x * blockDim.x + threadIdx.x;
    float x = ws[i] + b2[0];
    out[i] = 1.0f / (1.0f + expf(-x));
}

extern "C" void kernel_launch(void* const* d_in, const int* in_sizes, int n_in,
                              void* d_out, int out_size, void* d_ws, size_t ws_size,
                              hipStream_t stream)
{
    (void)in_sizes; (void)n_in; (void)out_size; (void)ws_size;
    const float* stm  = (const float*)d_in[0];
    const float* nstm = (const float*)d_in[1];
    const float* W1   = (const float*)d_in[2];
    const float* b1   = (const float*)d_in[3];
    const float* W2   = (const float*)d_in[4];
    const float* b2   = (const float*)d_in[5];
    float* out = (float*)d_out;
    float* ws  = (float*)d_ws;                                       // fp32 partials
    unsigned short* W1b = (unsigned short*)((char*)d_ws + W1B_OFF);  // bf16 W1 copy

    hipMemsetAsync(ws, 0, BATCH * sizeof(float), stream);
    cvt_w1<<<dim3((FOUT * FIN) / (256 * 8)), dim3(256), 0, stream>>>(W1, W1b);

    dim3 grid((FOUT / BN) * ((2 * BATCH) / BM));   // 4 * 256 = 1024 blocks
    pn_gemm<<<grid, dim3(256), 0, stream>>>(stm, nstm, W1b, b1, W2, ws);
    pn_finalize<<<dim3(BATCH / 256), dim3(256), 0, stream>>>(ws, b2, out);
}

// Round 8
// 153.506 us; speedup vs baseline: 1.8864x; 1.0529x over previous
//
#include <hip/hip_runtime.h>
#include <hip/hip_bf16.h>

#define BATCH 16384
#define FIN   768
#define FOUT  512

#define BK 64
#define NT (FIN / BK)   // 12 K-iterations

typedef __attribute__((ext_vector_type(8))) short short8;
typedef __attribute__((ext_vector_type(4))) float floatx4;

// packed fp32x2 -> bf16x2, round-to-nearest-even (gfx940+ VOP3)
__device__ __forceinline__ unsigned int cvt_pk_bf16(float a, float b) {
    unsigned int r;
    asm("v_cvt_pk_bf16_f32 %0, %1, %2" : "=v"(r) : "v"(a), "v"(b));
    return r;
}

// async 16B global -> LDS DMA; HW scatters lane i to ldsbase + i*16
__device__ __forceinline__ void load_lds_16(const void* g, void* l) {
    __builtin_amdgcn_global_load_lds(
        (const __attribute__((address_space(1))) unsigned int*)g,
        (__attribute__((address_space(3))) unsigned int*)l,
        16, 0, 0);
}

// one-shot W1 fp32 -> bf16 (393216 elems, 8 per thread, 192 blocks)
__global__ __launch_bounds__(256) void cvt_w1(
    const float* __restrict__ W1, unsigned short* __restrict__ W1b)
{
    int base = (blockIdx.x * 256 + threadIdx.x) * 8;
    float4 a = *(const float4*)(W1 + base);
    float4 b = *(const float4*)(W1 + base + 4);
    uint4 o;
    o.x = cvt_pk_bf16(a.x, a.y); o.y = cvt_pk_bf16(a.z, a.w);
    o.z = cvt_pk_bf16(b.x, b.y); o.w = cvt_pk_bf16(b.z, b.w);
    *(uint4*)(W1b + base) = o;
}

// One block = one CU: 64 batch rows x BOTH perspectives (128 GEMM rows) x all
// 512 features. X read exactly once chip-wide; W1b is L2-resident. Fully
// fused: clip + W2-dot + cross-wave LDS reduce + sigmoid -> d_out. No
// atomics, no workspace partials, no second kernel.
// LDS: XOR-swizzled (slot = chunk ^ (row&7), stride 64) -> conflict-free
// b128 reads AND writes. B staged by global_load_lds with the swizzle
// applied to the per-lane SOURCE address (dest must stay lane-ordered).
__global__ __launch_bounds__(1024, 4) void pn_gemm(
    const float* __restrict__ stm, const float* __restrict__ nstm,
    const unsigned short* __restrict__ W1b, const float* __restrict__ b1,
    const float* __restrict__ W2, const float* __restrict__ b2,
    float* __restrict__ out)
{
    __shared__ __align__(16) unsigned short As[128 * 64];  // 16 KB
    __shared__ __align__(16) unsigned short Bs[512 * 64];  // 64 KB

    const int tid  = threadIdx.x;
    const int lane = tid & 63;
    const int wave = tid >> 6;    // 0..15
    const int wrow = wave >> 3;   // 0 = stm rows (0..63), 1 = nstm rows (64..127)
    const int wcol = wave & 7;    // col tile: cols wcol*64 .. +63
    const int quad = lane >> 4;
    const int l16  = lane & 15;
    const int l7   = l16 & 7;

    const int b0 = blockIdx.x * 64;   // batch rows owned by this block

    // ---- A staging geometry: GEMM row = wave*8 + (lane&7), chunk = lane>>3
    const int arow = wave * 8 + (lane & 7);   // 0..127
    const int ac   = lane >> 3;               // 16B-chunk (8 bf16 = 8 fp32 src)
    const float* aSrc = (arow < 64)
        ? stm  + (size_t)(b0 + arow)      * FIN + ac * 8
        : nstm + (size_t)(b0 + arow - 64) * FIN + ac * 8;
    unsigned short* aDst = &As[arow * 64 + (ac ^ (arow & 7)) * 8];

    // ---- B staging: instr i covers rows i*128 + wave*8 + (lane>>3)
    const int brl  = lane >> 3;               // row within 8-group
    const int bg   = (lane & 7) ^ brl;        // swizzled source chunk

    floatx4 acc[4][4];
    #pragma unroll
    for (int i = 0; i < 4; ++i)
        #pragma unroll
        for (int j = 0; j < 4; ++j)
            acc[i][j] = (floatx4)0.0f;

    // prefetch A tile 0
    float4 ap0 = *(const float4*)(aSrc);
    float4 ap1 = *(const float4*)(aSrc + 4);

    for (int t = 0; t < NT; ++t) {
        const int kt = t * BK;
        __syncthreads();   // LDS of tile t-1 fully consumed

        // B: async DMA, swizzled source per lane, lane-ordered dest
        #pragma unroll
        for (int i = 0; i < 4; ++i) {
            const int row = i * 128 + wave * 8 + brl;
            load_lds_16(W1b + (size_t)row * FIN + kt + bg * 8,
                        &Bs[(i * 128 + wave * 8) * 64]);
        }
        // A: write prefetched regs (one b128 per thread, conflict-free)
        {
            uint4 o;
            o.x = cvt_pk_bf16(ap0.x, ap0.y); o.y = cvt_pk_bf16(ap0.z, ap0.w);
            o.z = cvt_pk_bf16(ap1.x, ap1.y); o.w = cvt_pk_bf16(ap1.z, ap1.w);
            *(uint4*)aDst = o;
        }
        // A: prefetch tile t+1 (covered by the DMA drain at the next barrier)
        if (t + 1 < NT) {
            ap0 = *(const float4*)(aSrc + kt + BK);
            ap1 = *(const float4*)(aSrc + kt + BK + 4);
        }
        __syncthreads();   // drains DMA (B ready) + A prefetch in flight

        #pragma unroll
        for (int s = 0; s < 2; ++s) {
            short8 af[4], bfr[4];
            #pragma unroll
            for (int mi = 0; mi < 4; ++mi) {
                const int m = wrow * 64 + mi * 16 + l16;
                af[mi] = *(const short8*)(&As[m * 64 + ((s * 4 + quad) ^ l7) * 8]);
            }
            #pragma unroll
            for (int ni = 0; ni < 4; ++ni) {
                const int n = wcol * 64 + ni * 16 + l16;
                bfr[ni] = *(const short8*)(&Bs[n * 64 + ((s * 4 + quad) ^ l7) * 8]);
            }
            #pragma unroll
            for (int mi = 0; mi < 4; ++mi)
                #pragma unroll
                for (int ni = 0; ni < 4; ++ni)
                    acc[mi][ni] = __builtin_amdgcn_mfma_f32_16x16x32_bf16(
                        af[mi], bfr[ni], acc[mi][ni], 0, 0, 0);
        }
    }

    // ---- fused epilogue. C/D layout: col = lane&15, row = quad*4 + reg.
    float b1v[4], w2v[4];
    #pragma unroll
    for (int ni = 0; ni < 4; ++ni) {
        int col = wcol * 64 + ni * 16 + l16;
        b1v[ni] = b1[col];
        w2v[ni] = W2[wrow * FOUT + col];   // wrow: 0 = stm half, 1 = nstm half
    }

    __syncthreads();                 // all MFMA LDS reads done; reuse As
    float* Epi = (float*)As;         // [128 rows][8 wcol] partials

    #pragma unroll
    for (int mi = 0; mi < 4; ++mi) {
        #pragma unroll
        for (int r = 0; r < 4; ++r) {
            float s = 0.0f;
            #pragma unroll
            for (int ni = 0; ni < 4; ++ni) {
                float h = acc[mi][ni][r] + b1v[ni];
                h = fminf(fmaxf(h, 0.0f), 1.0f);
                s += h * w2v[ni];
            }
            s += __shfl_xor(s, 1);
            s += __shfl_xor(s, 2);
            s += __shfl_xor(s, 4);
            s += __shfl_xor(s, 8);
            if (l16 == 0) {
                Epi[(wrow * 64 + mi * 16 + quad * 4 + r) * 8 + wcol] = s;
            }
        }
    }
    __syncthreads();

    if (tid < 64) {
        float x = b2[0];
        #pragma unroll
        for (int j = 0; j < 8; ++j)
            x += Epi[tid * 8 + j] + Epi[(tid + 64) * 8 + j];
        out[b0 + tid] = 1.0f / (1.0f + expf(-x));
    }
}

extern "C" void kernel_launch(void* const* d_in, const int* in_sizes, int n_in,
                              void* d_out, int out_size, void* d_ws, size_t ws_size,
                              hipStream_t stream)
{
    (void)in_sizes; (void)n_in; (void)out_size; (void)ws_size;
    const float* stm  = (const float*)d_in[0];
    const float* nstm = (const float*)d_in[1];
    const float* W1   = (const float*)d_in[2];
    const float* b1   = (const float*)d_in[3];
    const float* W2   = (const float*)d_in[4];
    const float* b2   = (const float*)d_in[5];
    float* out = (float*)d_out;
    unsigned short* W1b = (unsigned short*)d_ws;   // bf16 W1 copy (768 KB)

    cvt_w1<<<dim3((FOUT * FIN) / (256 * 8)), dim3(256), 0, stream>>>(W1, W1b);
    pn_gemm<<<dim3(BATCH / 64), dim3(1024), 0, stream>>>(
        stm, nstm, W1b, b1, W2, b2, out);
}

// Round 9
// 148.668 us; speedup vs baseline: 1.9477x; 1.0325x over previous
//
#include <hip/hip_runtime.h>
#include <hip/hip_bf16.h>

#define BATCH 16384
#define FIN   768
#define FOUT  512

#define BK 32
#define NT (FIN / BK)   // 24 K-iterations

typedef __attribute__((ext_vector_type(8))) short short8;
typedef __attribute__((ext_vector_type(4))) float floatx4;

// packed fp32x2 -> bf16x2, round-to-nearest-even (gfx940+ VOP3)
__device__ __forceinline__ unsigned int cvt_pk_bf16(float a, float b) {
    unsigned int r;
    asm("v_cvt_pk_bf16_f32 %0, %1, %2" : "=v"(r) : "v"(a), "v"(b));
    return r;
}

// async 16B global -> LDS DMA; HW scatters lane i to ldsbase + i*16
__device__ __forceinline__ void load_lds_16(const void* g, void* l) {
    __builtin_amdgcn_global_load_lds(
        (const __attribute__((address_space(1))) unsigned int*)g,
        (__attribute__((address_space(3))) unsigned int*)l,
        16, 0, 0);
}

// one-shot W1 fp32 -> bf16 (393216 elems, 8 per thread, 192 blocks)
__global__ __launch_bounds__(256) void cvt_w1(
    const float* __restrict__ W1, unsigned short* __restrict__ W1b)
{
    int base = (blockIdx.x * 256 + threadIdx.x) * 8;
    float4 a = *(const float4*)(W1 + base);
    float4 b = *(const float4*)(W1 + base + 4);
    uint4 o;
    o.x = cvt_pk_bf16(a.x, a.y); o.y = cvt_pk_bf16(a.z, a.w);
    o.z = cvt_pk_bf16(b.x, b.y); o.w = cvt_pk_bf16(b.z, b.w);
    *(uint4*)(W1b + base) = o;
}

// One block = one CU: 64 batch rows x both perspectives (128 GEMM rows) x all
// 512 features, fully fused epilogue (clip + W2-dot + LDS reduce + sigmoid).
// SINGLE barrier per K-iter, double-buffered A and B:
//   [publish A(t)] barrier [issue B-DMA(t+1) + A-load(t+1)] [MFMA on tile t]
// Staging for t+1 completes in the background of tile t's compute; the
// compiler's vmcnt/lgkm drain at the next barrier finds it already done.
// LDS 80 KB; XOR-swizzled (slot = chunk ^ (row&3), 4 chunks/row) => both
// stores and b128 reads hit the 8-cyc wave64 minimum (conflict-free).
__global__ __launch_bounds__(1024, 4) void pn_gemm(
    const float* __restrict__ stm, const float* __restrict__ nstm,
    const unsigned short* __restrict__ W1b, const float* __restrict__ b1,
    const float* __restrict__ W2, const float* __restrict__ b2,
    float* __restrict__ out)
{
    __shared__ __align__(16) unsigned short As[2][128 * 32];  // 2 x 8 KB
    __shared__ __align__(16) unsigned short Bs[2][512 * 32];  // 2 x 32 KB

    const int tid  = threadIdx.x;
    const int lane = tid & 63;
    const int wave = tid >> 6;    // 0..15
    const int wrow = wave >> 3;   // 0 = stm rows (0..63), 1 = nstm rows (64..127)
    const int wcol = wave & 7;    // col tile: cols wcol*64 .. +63
    const int quad = lane >> 4;
    const int l16  = lane & 15;
    const int l3   = l16 & 3;

    const int b0 = blockIdx.x * 64;   // batch rows owned by this block

    // ---- A staging (waves 0-7 only): thread covers row arow, chunk ach
    const int arow = tid >> 2;        // 0..127 (valid for tid < 512)
    const int ach  = tid & 3;         // 8-elem chunk within the 32-k tile
    const float* aSrc = nullptr;
    if (wave < 8)
        aSrc = ((arow < 64) ? stm  + (size_t)(b0 + arow) * FIN
                            : nstm + (size_t)(b0 + arow - 64) * FIN) + ach * 8;
    const int aOff = arow * 32 + (ach ^ (arow & 3)) * 8;   // swizzled dest

    // ---- B staging: 2 DMA instrs/wave, J = wave*2+i covers rows J*16..+15
    const int brow = lane >> 2;            // row within 16-group
    const int bch  = (lane & 3) ^ (brow & 3);   // swizzled SOURCE chunk

    floatx4 acc[4][4];
    #pragma unroll
    for (int i = 0; i < 4; ++i)
        #pragma unroll
        for (int j = 0; j < 4; ++j)
            acc[i][j] = (floatx4)0.0f;

    // ---- prologue: stage tile 0
    float4 ap0, ap1;
    if (wave < 8) {
        ap0 = *(const float4*)(aSrc);
        ap1 = *(const float4*)(aSrc + 4);
    }
    #pragma unroll
    for (int i = 0; i < 2; ++i) {
        const int J = wave * 2 + i;
        load_lds_16(W1b + (size_t)(J * 16 + brow) * FIN + bch * 8,
                    &Bs[0][J * 16 * 32]);
    }

    for (int t = 0; t < NT; ++t) {
        const int cur = t & 1;
        const int nxt = cur ^ 1;

        // publish A(t) (regs loaded last iter; As[cur] reads drained at barrier t-1)
        if (wave < 8) {
            uint4 o;
            o.x = cvt_pk_bf16(ap0.x, ap0.y); o.y = cvt_pk_bf16(ap0.z, ap0.w);
            o.z = cvt_pk_bf16(ap1.x, ap1.y); o.w = cvt_pk_bf16(ap1.z, ap1.w);
            *(uint4*)(&As[cur][aOff]) = o;
        }
        __syncthreads();   // drains B-DMA(t) + A-store(t); protects tile t-1 buffers

        // issue staging for t+1 — lands during tile t's compute
        if (t + 1 < NT) {
            const int kn = (t + 1) * BK;
            #pragma unroll
            for (int i = 0; i < 2; ++i) {
                const int J = wave * 2 + i;
                load_lds_16(W1b + (size_t)(J * 16 + brow) * FIN + kn + bch * 8,
                            &Bs[nxt][J * 16 * 32]);
            }
            if (wave < 8) {
                ap0 = *(const float4*)(aSrc + kn);
                ap1 = *(const float4*)(aSrc + kn + 4);
            }
        }

        // compute tile t
        short8 af[4], bfr[4];
        #pragma unroll
        for (int mi = 0; mi < 4; ++mi) {
            const int m = wrow * 64 + mi * 16 + l16;
            af[mi] = *(const short8*)(&As[cur][m * 32 + ((quad ^ l3) * 8)]);
        }
        #pragma unroll
        for (int ni = 0; ni < 4; ++ni) {
            const int n = wcol * 64 + ni * 16 + l16;
            bfr[ni] = *(const short8*)(&Bs[cur][n * 32 + ((quad ^ l3) * 8)]);
        }
        #pragma unroll
        for (int mi = 0; mi < 4; ++mi)
            #pragma unroll
            for (int ni = 0; ni < 4; ++ni)
                acc[mi][ni] = __builtin_amdgcn_mfma_f32_16x16x32_bf16(
                    af[mi], bfr[ni], acc[mi][ni], 0, 0, 0);
    }

    // ---- fused epilogue. C/D layout: col = lane&15, row = quad*4 + reg.
    float b1v[4], w2v[4];
    #pragma unroll
    for (int ni = 0; ni < 4; ++ni) {
        int col = wcol * 64 + ni * 16 + l16;
        b1v[ni] = b1[col];
        w2v[ni] = W2[wrow * FOUT + col];   // wrow: 0 = stm half, 1 = nstm half
    }

    __syncthreads();                 // all MFMA LDS reads done; reuse As
    float* Epi = (float*)As;         // [128 rows][8 wcol] partials (4 KB)

    #pragma unroll
    for (int mi = 0; mi < 4; ++mi) {
        #pragma unroll
        for (int r = 0; r < 4; ++r) {
            float s = 0.0f;
            #pragma unroll
            for (int ni = 0; ni < 4; ++ni) {
                float h = acc[mi][ni][r] + b1v[ni];
                h = fminf(fmaxf(h, 0.0f), 1.0f);
                s += h * w2v[ni];
            }
            s += __shfl_xor(s, 1);
            s += __shfl_xor(s, 2);
            s += __shfl_xor(s, 4);
            s += __shfl_xor(s, 8);
            if (l16 == 0) {
                Epi[(wrow * 64 + mi * 16 + quad * 4 + r) * 8 + wcol] = s;
            }
        }
    }
    __syncthreads();

    if (tid < 64) {
        float x = b2[0];
        #pragma unroll
        for (int j = 0; j < 8; ++j)
            x += Epi[tid * 8 + j] + Epi[(tid + 64) * 8 + j];
        out[b0 + tid] = 1.0f / (1.0f + expf(-x));
    }
}

extern "C" void kernel_launch(void* const* d_in, const int* in_sizes, int n_in,
                              void* d_out, int out_size, void* d_ws, size_t ws_size,
                              hipStream_t stream)
{
    (void)in_sizes; (void)n_in; (void)out_size; (void)ws_size;
    const float* stm  = (const float*)d_in[0];
    const float* nstm = (const float*)d_in[1];
    const float* W1   = (const float*)d_in[2];
    const float* b1   = (const float*)d_in[3];
    const float* W2   = (const float*)d_in[4];
    const float* b2   = (const float*)d_in[5];
    float* out = (float*)d_out;
    unsigned short* W1b = (unsigned short*)d_ws;   // bf16 W1 copy (768 KB)

    cvt_w1<<<dim3((FOUT * FIN) / (256 * 8)), dim3(256), 0, stream>>>(W1, W1b);
    pn_gemm<<<dim3(BATCH / 64), dim3(1024), 0, stream>>>(
        stm, nstm, W1b, b1, W2, b2, out);
}